// Round 21
// baseline (850.791 us; speedup 1.0000x reference)
//
#include <hip/hip_runtime.h>

typedef unsigned short u16;
typedef unsigned int u32;
typedef __attribute__((ext_vector_type(8))) short bf16x8;
typedef __attribute__((ext_vector_type(4))) float f32x4;
typedef __attribute__((ext_vector_type(8))) unsigned short u16x8;
typedef __attribute__((ext_vector_type(4))) unsigned short u16x4;
typedef __attribute__((ext_vector_type(4))) u32 u32x4;

#define MFMA16 __builtin_amdgcn_mfma_f32_16x16x32_bf16

__device__ __forceinline__ u16 f2bf(float f) {
  unsigned u = __float_as_uint(f);
  u += 0x7fffu + ((u >> 16) & 1u);
  return (u16)(u >> 16);
}

__device__ __forceinline__ void async16(void* lds, const void* g) {
  __builtin_amdgcn_global_load_lds(
      (const __attribute__((address_space(1))) unsigned int*)g,
      (__attribute__((address_space(3))) unsigned int*)lds, 16, 0, 0);
}

// ---------------- fused f32 -> bf16 conversion (one launch, 3 regions) -----
__global__ void convert_all(const float* __restrict__ x, const float* __restrict__ Win,
                            const float* __restrict__ Wout, u16* __restrict__ xo,
                            u16* __restrict__ wino, u16* __restrict__ wouto) {
  const int nx = 16777216 / 4, nw = 12582912 / 4, no = 4194304 / 4;
  int i = blockIdx.x * blockDim.x + threadIdx.x;
  int st = gridDim.x * blockDim.x;
  for (; i < nx + nw + no; i += st) {
    const float4* src; ushort4* dst; int j;
    if (i < nx) { src = (const float4*)x; dst = (ushort4*)xo; j = i; }
    else if (i < nx + nw) { src = (const float4*)Win; dst = (ushort4*)wino; j = i - nx; }
    else { src = (const float4*)Wout; dst = (ushort4*)wouto; j = i - nx - nw; }
    float4 f = src[j];
    ushort4 o;
    o.x = f2bf(f.x); o.y = f2bf(f.y); o.z = f2bf(f.z); o.w = f2bf(f.w);
    dst[j] = o;
  }
}

// ============ 256x256 GEMM core, 2-window schedule (r12/r20, banked) =======
#define GEMM256_CORE(A_, B_)                                                    \
  __shared__ __align__(16) char lds[131072];                                    \
  const int tid = threadIdx.x;                                                  \
  const int lane = tid & 63, w = tid >> 6;                                      \
  const int wr = w >> 2, wc = w & 3;                                            \
  const int fr = lane & 15, fq = lane >> 4;                                     \
  const int lrA = tid >> 3, ccA = tid & 7, w8 = w << 3;                         \
  f32x4 acc[8][4] = {};                                                         \
  const u16* Abase = A_ + (size_t)tm * 2048;                                    \
  const u16* Bbase = B_ + (size_t)tn * 2048;                                    \
  auto stageA = [&](int mh, int kt, char* buf) {                                \
    _Pragma("unroll") for (int it = 0; it < 2; ++it) {                          \
      int lrt = it * 64 + lrA;                                                  \
      int row = mh * 64 + (lrt & 63) + ((lrt & 64) << 1);                       \
      const u16* src = Abase + (size_t)row * 2048 + kt + ((ccA ^ (row & 7)) << 3); \
      int lr0 = it * 64 + w8;                                                   \
      int row0 = mh * 64 + (lr0 & 63) + ((lr0 & 64) << 1);                      \
      async16(buf + row0 * 128, src);                                           \
    }                                                                           \
  };                                                                            \
  auto stageB = [&](int nh, int kt, char* buf) {                                \
    _Pragma("unroll") for (int it = 0; it < 2; ++it) {                          \
      int lrt = it * 64 + lrA;                                                  \
      int nr = ((lrt >> 5) << 6) + nh * 32 + (lrt & 31);                        \
      const u16* src = Bbase + (size_t)nr * 2048 + kt + ((ccA ^ (nr & 7)) << 3); \
      int lr0 = it * 64 + w8;                                                   \
      int nr0 = ((lr0 >> 5) << 6) + nh * 32 + (lr0 & 31);                       \
      async16(buf + 32768 + nr0 * 128, src);                                    \
    }                                                                           \
  };                                                                            \
  stageA(0, 0, lds); stageB(0, 0, lds); stageB(1, 0, lds); stageA(1, 0, lds);   \
  for (int t = 0; t < 32; ++t) {                                                \
    char* cur = lds + (t & 1) * 65536;                                          \
    char* nxt = lds + ((t + 1) & 1) * 65536;                                    \
    const int ktn = (t + 1) * 64;                                               \
    const bool more = (t + 1 < 32);                                             \
    asm volatile("s_waitcnt vmcnt(2)" ::: "memory");                            \
    __builtin_amdgcn_s_barrier();                                               \
    asm volatile("" ::: "memory");                                              \
    bf16x8 af[4][2], bfr[4][2];                                                 \
    _Pragma("unroll") for (int i = 0; i < 4; ++i) {                             \
      int rr = wr * 128 + i * 16 + fr;                                          \
      _Pragma("unroll") for (int ks = 0; ks < 2; ++ks)                          \
        af[i][ks] = *(const bf16x8*)(cur + rr * 128 +                           \
                                     (((ks * 4 + fq) ^ (rr & 7)) << 4));        \
    }                                                                           \
    _Pragma("unroll") for (int j = 0; j < 4; ++j) {                             \
      int nr = wc * 64 + j * 16 + fr;                                           \
      _Pragma("unroll") for (int ks = 0; ks < 2; ++ks)                          \
        bfr[j][ks] = *(const bf16x8*)(cur + 32768 + nr * 128 +                  \
                                      (((ks * 4 + fq) ^ (nr & 7)) << 4));       \
    }                                                                           \
    if (more) { stageA(0, ktn, nxt); stageB(0, ktn, nxt); }                     \
    __builtin_amdgcn_s_setprio(1);                                              \
    _Pragma("unroll") for (int ks = 0; ks < 2; ++ks)                            \
      _Pragma("unroll") for (int i = 0; i < 4; ++i)                             \
        _Pragma("unroll") for (int j = 0; j < 4; ++j)                           \
          acc[i][j] = MFMA16(af[i][ks], bfr[j][ks], acc[i][j], 0, 0, 0);        \
    __builtin_amdgcn_s_setprio(0);                                              \
    if (more) asm volatile("s_waitcnt vmcnt(4)" ::: "memory");                  \
    else      asm volatile("s_waitcnt vmcnt(0)" ::: "memory");                  \
    __builtin_amdgcn_s_barrier();                                               \
    asm volatile("" ::: "memory");                                              \
    bf16x8 ag[4][2];                                                            \
    _Pragma("unroll") for (int i = 0; i < 4; ++i) {                             \
      int rr = wr * 128 + 64 + i * 16 + fr;                                     \
      _Pragma("unroll") for (int ks = 0; ks < 2; ++ks)                          \
        ag[i][ks] = *(const bf16x8*)(cur + rr * 128 +                           \
                                     (((ks * 4 + fq) ^ (rr & 7)) << 4));        \
    }                                                                           \
    if (more) { stageB(1, ktn, nxt); stageA(1, ktn, nxt); }                     \
    __builtin_amdgcn_s_setprio(1);                                              \
    _Pragma("unroll") for (int ks = 0; ks < 2; ++ks)                            \
      _Pragma("unroll") for (int i = 0; i < 4; ++i)                             \
        _Pragma("unroll") for (int j = 0; j < 4; ++j)                           \
          acc[4 + i][j] = MFMA16(ag[i][ks], bfr[j][ks], acc[4 + i][j], 0, 0, 0);\
    __builtin_amdgcn_s_setprio(0);                                              \
  }

// qkv: Q,K -> [B,H,T,D] (direct); V -> Vt via LDS-transpose epilogue (r16)
__global__ __launch_bounds__(512, 2) void gemm_qkv8(
    const u16* __restrict__ A, const u16* __restrict__ B,
    u16* __restrict__ Qb, u16* __restrict__ Kb, u16* __restrict__ Vtb) {
  int id = blockIdx.x;
  int swz = (id & 7) * 96 + (id >> 3);
  const int tm = (swz / 24) * 256, tn = (swz % 24) * 256;
  GEMM256_CORE(A, B)
  if (tn < 4096) {
#pragma unroll
    for (int J = 0; J < 4; ++J) {
      int n = tn + wc * 64 + J * 16 + fr;
      int which = n >> 11, h = (n >> 7) & 15, d = n & 127;
      u16* dst = which == 0 ? Qb : Kb;
#pragma unroll
      for (int I = 0; I < 8; ++I)
#pragma unroll
        for (int rr = 0; rr < 4; ++rr) {
          int m = tm + wr * 128 + I * 16 + fq * 4 + rr;
          int bb = m >> 11, tt = m & 2047;
          dst[((size_t)((bb * 16 + h) * 2048 + tt) << 7) + d] = f2bf(acc[I][J][rr]);
        }
    }
  } else {
    __syncthreads();
    u16* my = (u16*)(lds) + w * 8192;
#pragma unroll
    for (int J = 0; J < 4; ++J)
#pragma unroll
      for (int I = 0; I < 8; ++I) {
        u16x4 pk;
#pragma unroll
        for (int rr = 0; rr < 4; ++rr) pk[rr] = f2bf(acc[I][J][rr]);
        *(u16x4*)&my[(J * 16 + fr) * 128 + I * 16 + fq * 4] = pk;
      }
    const int bb = tm >> 11;
    const int hh = wc >> 1;
    const int h = ((tn >> 7) | hh) & 15;
    const int dbase = (wc & 1) * 64;
    const int tbase = (tm & 2047) + wr * 128;
    u16* Vw = Vtb + (size_t)(bb * 16 + h) * 262144;
#pragma unroll
    for (int it = 0; it < 16; ++it) {
      int chunk = it * 64 + lane;
      int nl = chunk >> 4, cc = chunk & 15;
      u16x8 v8 = *(const u16x8*)&my[nl * 128 + cc * 8];
      *(u16x8*)&Vw[(size_t)(dbase + nl) * 2048 + tbase + cc * 8] = v8;
    }
  }
}

// out-projection: C f32 [8192][2048]
__global__ __launch_bounds__(512, 2) void gemm_out8(
    const u16* __restrict__ A, const u16* __restrict__ B, float* __restrict__ C) {
  int id = blockIdx.x;
  int swz = (id & 7) * 32 + (id >> 3);
  const int tm = (swz / 8) * 256, tn = (swz % 8) * 256;
  GEMM256_CORE(A, B)
#pragma unroll
  for (int J = 0; J < 4; ++J) {
    int n = tn + wc * 64 + J * 16 + fr;
#pragma unroll
    for (int I = 0; I < 8; ++I)
#pragma unroll
      for (int rr = 0; rr < 4; ++rr) {
        int m = tm + wr * 128 + I * 16 + fq * 4 + rr;
        C[(size_t)m * 2048 + n] = acc[I][J][rr];
      }
  }
}

// ---------------- flash attention v21: interleaved q-block pair ------------
// Block handles q-blocks {by, 15-by} CONCURRENTLY in one tile loop: each
// staged K/V tile serves both sets. Stagings+barriers per grid drop 34%
// (19456 -> 12800); two independent QKT->softmax->PV chains per barrier
// window. Per-set body = attn14 verbatim (lambda-parameterized state).
// 512 blocks, compute-balanced (34 q-tile-units each); launch_bounds(512,4)
// caps VGPR at 128 (~112 naive). LDS 48K; P region reused A-then-B
// (wave-private rows, DS in-order per wave -> WAR safe).
__global__ __launch_bounds__(512, 4) void attn21(
    const u16* __restrict__ Q, const u16* __restrict__ K,
    const u16* __restrict__ Vt, u16* __restrict__ Y) {
  __shared__ __align__(16) char smem[49152];
  char* lK = smem;
  char* lV = smem + 16384;
  char* lP = smem + 32768;
  const int tid = threadIdx.x;
  const int lane = tid & 63, w = tid >> 6;
  const int fr = lane & 15, fq = lane >> 4;
  const int pair = blockIdx.x, by = blockIdx.y;
  const size_t hoff = (size_t)pair * 262144;
  const u16* Qh = Q + hoff;
  const u16* Kh = K + hoff;
  const u16* Vth = Vt + hoff;
  const int b = pair >> 4, h = pair & 15;
  const float c1 = 0.08838834764831845f * 1.4426950408889634f;
  const float THR = 11.5f;

  const int qbA = by, qbB = 15 - by;
  const int qwA = qbA * 128 + w * 16;
  const int qwB = qbB * 128 + w * 16;
  const int NT = 2 * qbB + 2;                // qbB >= qbA, so B spans all tiles

  int ksr[2], kcc[2], vdr[2], vcc[2];
#pragma unroll
  for (int it = 0; it < 2; ++it) {
    int idx = it * 512 + tid;
    ksr[it] = idx >> 4; kcc[it] = idx & 15;
    vdr[it] = idx >> 3; vcc[it] = idx & 7;
  }

  bf16x8 qfA[4], qfB[4];
#pragma unroll
  for (int ks = 0; ks < 4; ++ks) {
    qfA[ks] = *(const bf16x8*)&Qh[(size_t)(qwA + fr) * 128 + ks * 32 + fq * 8];
    qfB[ks] = *(const bf16x8*)&Qh[(size_t)(qwB + fr) * 128 + ks * 32 + fq * 8];
  }

  f32x4 oA[8] = {}, oB[8] = {};
  float m2A[4], lsA[4], m2B[4], lsB[4];
#pragma unroll
  for (int r = 0; r < 4; ++r) {
    m2A[r] = -1e30f; lsA[r] = 0.f;
    m2B[r] = -1e30f; lsB[r] = 0.f;
  }

  u32x4 kst[2], vst[2];
#pragma unroll
  for (int it = 0; it < 2; ++it) {
    kst[it] = *(const u32x4*)&Kh[(size_t)ksr[it] * 128 + kcc[it] * 8];
    vst[it] = *(const u32x4*)&Vth[(size_t)vdr[it] * 2048 + vcc[it] * 8];
  }

  // per-set tile body: attn14 verbatim over parameterized state
  auto proc = [&](int kv0, int qw, bf16x8 (&qf)[4], f32x4 (&o)[8],
                  float (&m2)[4], float (&ls)[4]) {
    f32x4 sc[4] = {};
#pragma unroll
    for (int j = 0; j < 4; ++j) {
      int s = j * 16 + fr;
#pragma unroll
      for (int ks = 0; ks < 4; ++ks) {
        bf16x8 kf = *(const bf16x8*)(lK + s * 256 + (((ks * 32 + fq * 8) * 2) ^ ((s & 7) << 4)));
        sc[j] = MFMA16(qf[ks], kf, sc[j], 0, 0, 0);
      }
    }
    if (kv0 + 64 > qw) {
      int rowb = qw + fq * 4;
#pragma unroll
      for (int j = 0; j < 4; ++j) {
        int col = kv0 + j * 16 + fr;
#pragma unroll
        for (int r = 0; r < 4; ++r)
          if (col > rowb + r) sc[j][r] = -3e38f;
      }
    }
    float lmax[4];
    bool trip = false;
#pragma unroll
    for (int r = 0; r < 4; ++r) {
      lmax[r] = fmaxf(fmaxf(sc[0][r], sc[1][r]), fmaxf(sc[2][r], sc[3][r]));
      trip = trip || (lmax[r] * c1 > m2[r] + THR);
    }
    if (__any(trip)) {
#pragma unroll
      for (int r = 0; r < 4; ++r) {
        float v = lmax[r];
        v = fmaxf(v, __shfl_xor(v, 1));
        v = fmaxf(v, __shfl_xor(v, 2));
        v = fmaxf(v, __shfl_xor(v, 4));
        v = fmaxf(v, __shfl_xor(v, 8));
        v *= c1;
        float mn = fmaxf(m2[r], v);
        float corr = __builtin_amdgcn_exp2f(m2[r] - mn);
        m2[r] = mn;
        ls[r] *= corr;
#pragma unroll
        for (int n = 0; n < 8; ++n) o[n][r] *= corr;
      }
    }
#pragma unroll
    for (int r = 0; r < 4; ++r) {
      int prow = w * 16 + fq * 4 + r;
      float rs = 0.f;
#pragma unroll
      for (int j = 0; j < 4; ++j) {
        float p = __builtin_amdgcn_exp2f(sc[j][r] * c1 - m2[r]);
        rs += p;
        *(u16*)(lP + prow * 128 + (((j * 16 + fr) * 2) ^ ((prow & 7) << 4))) = f2bf(p);
      }
      ls[r] += rs;
    }
    bf16x8 pf[2];
    {
      int prow = w * 16 + fr;
#pragma unroll
      for (int k2 = 0; k2 < 2; ++k2)
        pf[k2] = *(const bf16x8*)(lP + prow * 128 + ((k2 * 64 + fq * 16) ^ ((prow & 7) << 4)));
    }
#pragma unroll
    for (int n = 0; n < 8; ++n) {
      int d = n * 16 + fr;
#pragma unroll
      for (int k2 = 0; k2 < 2; ++k2) {
        bf16x8 vf = *(const bf16x8*)(lV + d * 128 + ((k2 * 64 + fq * 16) ^ ((d & 7) << 4)));
        o[n] = MFMA16(pf[k2], vf, o[n], 0, 0, 0);
      }
    }
  };

  for (int t = 0; t < NT; ++t) {
    const int kv0 = t * 64;
#pragma unroll
    for (int it = 0; it < 2; ++it) {
      *(u32x4*)(lK + ksr[it] * 256 + ((kcc[it] ^ (ksr[it] & 7)) << 4)) = kst[it];
      *(u32x4*)(lV + vdr[it] * 128 + ((vcc[it] ^ (vdr[it] & 7)) << 4)) = vst[it];
    }
    if (t + 1 < NT) {
      const int nk = kv0 + 64;
#pragma unroll
      for (int it = 0; it < 2; ++it) {
        kst[it] = *(const u32x4*)&Kh[(size_t)(nk + ksr[it]) * 128 + kcc[it] * 8];
        vst[it] = *(const u32x4*)&Vth[(size_t)vdr[it] * 2048 + nk + vcc[it] * 8];
      }
    }
    __syncthreads();  // K,V of tile t visible

    if (kv0 <= qwA + 15) proc(kv0, qwA, qfA, oA, m2A, lsA);  // set A (ends early)
    if (kv0 <= qwB + 15) proc(kv0, qwB, qfB, oB, m2B, lsB);  // set B

    __syncthreads();  // all reads done before next tile's staging writes
  }

  // epilogue: both sets
#pragma unroll
  for (int s2 = 0; s2 < 2; ++s2) {
    const int qw = s2 ? qwB : qwA;
    f32x4* o = s2 ? oB : oA;
    float* ls = s2 ? lsB : lsA;
    float inv[4];
#pragma unroll
    for (int r = 0; r < 4; ++r) {
      float s = ls[r];
      s += __shfl_xor(s, 1);
      s += __shfl_xor(s, 2);
      s += __shfl_xor(s, 4);
      s += __shfl_xor(s, 8);
      inv[r] = 1.f / s;
    }
#pragma unroll
    for (int n = 0; n < 8; ++n)
#pragma unroll
      for (int r = 0; r < 4; ++r) {
        int tt = qw + fq * 4 + r;
        Y[((size_t)(b * 2048 + tt) * 2048) + h * 128 + n * 16 + fr] = f2bf(o[n][r] * inv[r]);
      }
  }
}

// ---------------------------------------------------------------------------
extern "C" void kernel_launch(void* const* d_in, const int* in_sizes, int n_in,
                              void* d_out, int out_size, void* d_ws, size_t ws_size,
                              hipStream_t stream) {
  const float* x = (const float*)d_in[0];
  const float* Win = (const float*)d_in[1];
  const float* Wout = (const float*)d_in[2];
  float* out = (float*)d_out;
  char* ws = (char*)d_ws;

  u16* x_bf   = (u16*)(ws);                  // 33554432 B
  u16* win_bf = (u16*)(ws + 33554432);       // 25165824 B
  u16* wout_bf= (u16*)(ws + 58720256);       //  8388608 B
  u16* Qb     = (u16*)(ws + 67108864);       // 33554432 B
  u16* Kb     = (u16*)(ws + 100663296);      // 33554432 B
  u16* Vtb    = (u16*)(ws + 134217728);      // 33554432 B (V^T, fused epilogue)
  u16* y_bf   = (u16*)(ws + 167772160);      // 33554432 B  (total 192 MiB)

  convert_all<<<2048, 256, 0, stream>>>(x, Win, Wout, x_bf, win_bf, wout_bf);

  gemm_qkv8<<<768, 512, 0, stream>>>(x_bf, win_bf, Qb, Kb, Vtb);
  attn21<<<dim3(64, 8), 512, 0, stream>>>(Qb, Kb, Vtb, y_bf);
  gemm_out8<<<256, 512, 0, stream>>>(y_bf, wout_bf, out);
}

// Round 22
// 441.719 us; speedup vs baseline: 1.9261x; 1.9261x over previous
//
#include <hip/hip_runtime.h>

typedef unsigned short u16;
typedef unsigned int u32;
typedef __attribute__((ext_vector_type(8))) short bf16x8;
typedef __attribute__((ext_vector_type(4))) float f32x4;
typedef __attribute__((ext_vector_type(8))) unsigned short u16x8;
typedef __attribute__((ext_vector_type(4))) unsigned short u16x4;
typedef __attribute__((ext_vector_type(4))) u32 u32x4;

#define MFMA16 __builtin_amdgcn_mfma_f32_16x16x32_bf16

__device__ __forceinline__ u16 f2bf(float f) {
  unsigned u = __float_as_uint(f);
  u += 0x7fffu + ((u >> 16) & 1u);
  return (u16)(u >> 16);
}

__device__ __forceinline__ void async16(void* lds, const void* g) {
  __builtin_amdgcn_global_load_lds(
      (const __attribute__((address_space(1))) unsigned int*)g,
      (__attribute__((address_space(3))) unsigned int*)lds, 16, 0, 0);
}

// ---------------- fused f32 -> bf16 conversion (one launch, 3 regions) -----
__global__ void convert_all(const float* __restrict__ x, const float* __restrict__ Win,
                            const float* __restrict__ Wout, u16* __restrict__ xo,
                            u16* __restrict__ wino, u16* __restrict__ wouto) {
  const int nx = 16777216 / 4, nw = 12582912 / 4, no = 4194304 / 4;
  int i = blockIdx.x * blockDim.x + threadIdx.x;
  int st = gridDim.x * blockDim.x;
  for (; i < nx + nw + no; i += st) {
    const float4* src; ushort4* dst; int j;
    if (i < nx) { src = (const float4*)x; dst = (ushort4*)xo; j = i; }
    else if (i < nx + nw) { src = (const float4*)Win; dst = (ushort4*)wino; j = i - nx; }
    else { src = (const float4*)Wout; dst = (ushort4*)wouto; j = i - nx - nw; }
    float4 f = src[j];
    ushort4 o;
    o.x = f2bf(f.x); o.y = f2bf(f.y); o.z = f2bf(f.z); o.w = f2bf(f.w);
    dst[j] = o;
  }
}

// ============ 256x256 GEMM core, 2-window schedule (r12/r20, banked) =======
#define GEMM256_CORE(A_, B_)                                                    \
  __shared__ __align__(16) char lds[131072];                                    \
  const int tid = threadIdx.x;                                                  \
  const int lane = tid & 63, w = tid >> 6;                                      \
  const int wr = w >> 2, wc = w & 3;                                            \
  const int fr = lane & 15, fq = lane >> 4;                                     \
  const int lrA = tid >> 3, ccA = tid & 7, w8 = w << 3;                         \
  f32x4 acc[8][4] = {};                                                         \
  const u16* Abase = A_ + (size_t)tm * 2048;                                    \
  const u16* Bbase = B_ + (size_t)tn * 2048;                                    \
  auto stageA = [&](int mh, int kt, char* buf) {                                \
    _Pragma("unroll") for (int it = 0; it < 2; ++it) {                          \
      int lrt = it * 64 + lrA;                                                  \
      int row = mh * 64 + (lrt & 63) + ((lrt & 64) << 1);                       \
      const u16* src = Abase + (size_t)row * 2048 + kt + ((ccA ^ (row & 7)) << 3); \
      int lr0 = it * 64 + w8;                                                   \
      int row0 = mh * 64 + (lr0 & 63) + ((lr0 & 64) << 1);                      \
      async16(buf + row0 * 128, src);                                           \
    }                                                                           \
  };                                                                            \
  auto stageB = [&](int nh, int kt, char* buf) {                                \
    _Pragma("unroll") for (int it = 0; it < 2; ++it) {                          \
      int lrt = it * 64 + lrA;                                                  \
      int nr = ((lrt >> 5) << 6) + nh * 32 + (lrt & 31);                        \
      const u16* src = Bbase + (size_t)nr * 2048 + kt + ((ccA ^ (nr & 7)) << 3); \
      int lr0 = it * 64 + w8;                                                   \
      int nr0 = ((lr0 >> 5) << 6) + nh * 32 + (lr0 & 31);                       \
      async16(buf + 32768 + nr0 * 128, src);                                    \
    }                                                                           \
  };                                                                            \
  stageA(0, 0, lds); stageB(0, 0, lds); stageB(1, 0, lds); stageA(1, 0, lds);   \
  for (int t = 0; t < 32; ++t) {                                                \
    char* cur = lds + (t & 1) * 65536;                                          \
    char* nxt = lds + ((t + 1) & 1) * 65536;                                    \
    const int ktn = (t + 1) * 64;                                               \
    const bool more = (t + 1 < 32);                                             \
    asm volatile("s_waitcnt vmcnt(2)" ::: "memory");                            \
    __builtin_amdgcn_s_barrier();                                               \
    asm volatile("" ::: "memory");                                              \
    bf16x8 af[4][2], bfr[4][2];                                                 \
    _Pragma("unroll") for (int i = 0; i < 4; ++i) {                             \
      int rr = wr * 128 + i * 16 + fr;                                          \
      _Pragma("unroll") for (int ks = 0; ks < 2; ++ks)                          \
        af[i][ks] = *(const bf16x8*)(cur + rr * 128 +                           \
                                     (((ks * 4 + fq) ^ (rr & 7)) << 4));        \
    }                                                                           \
    _Pragma("unroll") for (int j = 0; j < 4; ++j) {                             \
      int nr = wc * 64 + j * 16 + fr;                                           \
      _Pragma("unroll") for (int ks = 0; ks < 2; ++ks)                          \
        bfr[j][ks] = *(const bf16x8*)(cur + 32768 + nr * 128 +                  \
                                      (((ks * 4 + fq) ^ (nr & 7)) << 4));       \
    }                                                                           \
    if (more) { stageA(0, ktn, nxt); stageB(0, ktn, nxt); }                     \
    __builtin_amdgcn_s_setprio(1);                                              \
    _Pragma("unroll") for (int ks = 0; ks < 2; ++ks)                            \
      _Pragma("unroll") for (int i = 0; i < 4; ++i)                             \
        _Pragma("unroll") for (int j = 0; j < 4; ++j)                           \
          acc[i][j] = MFMA16(af[i][ks], bfr[j][ks], acc[i][j], 0, 0, 0);        \
    __builtin_amdgcn_s_setprio(0);                                              \
    if (more) asm volatile("s_waitcnt vmcnt(4)" ::: "memory");                  \
    else      asm volatile("s_waitcnt vmcnt(0)" ::: "memory");                  \
    __builtin_amdgcn_s_barrier();                                               \
    asm volatile("" ::: "memory");                                              \
    bf16x8 ag[4][2];                                                            \
    _Pragma("unroll") for (int i = 0; i < 4; ++i) {                             \
      int rr = wr * 128 + 64 + i * 16 + fr;                                     \
      _Pragma("unroll") for (int ks = 0; ks < 2; ++ks)                          \
        ag[i][ks] = *(const bf16x8*)(cur + rr * 128 +                           \
                                     (((ks * 4 + fq) ^ (rr & 7)) << 4));        \
    }                                                                           \
    if (more) { stageB(1, ktn, nxt); stageA(1, ktn, nxt); }                     \
    __builtin_amdgcn_s_setprio(1);                                              \
    _Pragma("unroll") for (int ks = 0; ks < 2; ++ks)                            \
      _Pragma("unroll") for (int i = 0; i < 4; ++i)                             \
        _Pragma("unroll") for (int j = 0; j < 4; ++j)                           \
          acc[4 + i][j] = MFMA16(ag[i][ks], bfr[j][ks], acc[4 + i][j], 0, 0, 0);\
    __builtin_amdgcn_s_setprio(0);                                              \
  }

// qkv: Q,K -> [B,H,T,D] (direct); V -> Vt via LDS-transpose epilogue (r16)
__global__ __launch_bounds__(512, 2) void gemm_qkv8(
    const u16* __restrict__ A, const u16* __restrict__ B,
    u16* __restrict__ Qb, u16* __restrict__ Kb, u16* __restrict__ Vtb) {
  int id = blockIdx.x;
  int swz = (id & 7) * 96 + (id >> 3);
  const int tm = (swz / 24) * 256, tn = (swz % 24) * 256;
  GEMM256_CORE(A, B)
  if (tn < 4096) {
#pragma unroll
    for (int J = 0; J < 4; ++J) {
      int n = tn + wc * 64 + J * 16 + fr;
      int which = n >> 11, h = (n >> 7) & 15, d = n & 127;
      u16* dst = which == 0 ? Qb : Kb;
#pragma unroll
      for (int I = 0; I < 8; ++I)
#pragma unroll
        for (int rr = 0; rr < 4; ++rr) {
          int m = tm + wr * 128 + I * 16 + fq * 4 + rr;
          int bb = m >> 11, tt = m & 2047;
          dst[((size_t)((bb * 16 + h) * 2048 + tt) << 7) + d] = f2bf(acc[I][J][rr]);
        }
    }
  } else {
    __syncthreads();
    u16* my = (u16*)(lds) + w * 8192;
#pragma unroll
    for (int J = 0; J < 4; ++J)
#pragma unroll
      for (int I = 0; I < 8; ++I) {
        u16x4 pk;
#pragma unroll
        for (int rr = 0; rr < 4; ++rr) pk[rr] = f2bf(acc[I][J][rr]);
        *(u16x4*)&my[(J * 16 + fr) * 128 + I * 16 + fq * 4] = pk;
      }
    const int bb = tm >> 11;
    const int hh = wc >> 1;
    const int h = ((tn >> 7) | hh) & 15;
    const int dbase = (wc & 1) * 64;
    const int tbase = (tm & 2047) + wr * 128;
    u16* Vw = Vtb + (size_t)(bb * 16 + h) * 262144;
#pragma unroll
    for (int it = 0; it < 16; ++it) {
      int chunk = it * 64 + lane;
      int nl = chunk >> 4, cc = chunk & 15;
      u16x8 v8 = *(const u16x8*)&my[nl * 128 + cc * 8];
      *(u16x8*)&Vw[(size_t)(dbase + nl) * 2048 + tbase + cc * 8] = v8;
    }
  }
}

// out-projection: C f32 [8192][2048]
__global__ __launch_bounds__(512, 2) void gemm_out8(
    const u16* __restrict__ A, const u16* __restrict__ B, float* __restrict__ C) {
  int id = blockIdx.x;
  int swz = (id & 7) * 32 + (id >> 3);
  const int tm = (swz / 8) * 256, tn = (swz % 8) * 256;
  GEMM256_CORE(A, B)
#pragma unroll
  for (int J = 0; J < 4; ++J) {
    int n = tn + wc * 64 + J * 16 + fr;
#pragma unroll
    for (int I = 0; I < 8; ++I)
#pragma unroll
      for (int rr = 0; rr < 4; ++rr) {
        int m = tm + wr * 128 + I * 16 + fq * 4 + rr;
        C[(size_t)m * 2048 + n] = acc[I][J][rr];
      }
  }
}

// ---------------- flash attention: attn14 (443us state, banked final) ------
__global__ __launch_bounds__(512, 4) void attn14(
    const u16* __restrict__ Q, const u16* __restrict__ K,
    const u16* __restrict__ Vt, u16* __restrict__ Y) {
  __shared__ __align__(16) char smem[49152];
  char* lK = smem;
  char* lV = smem + 16384;
  char* lP = smem + 32768;
  const int tid = threadIdx.x;
  const int lane = tid & 63, w = tid >> 6;
  const int fr = lane & 15, fq = lane >> 4;
  const int pair = blockIdx.x;
  const int qb = 15 - (int)blockIdx.y;       // LPT: longest blocks first
  const size_t hoff = (size_t)pair * 262144;
  const u16* Qh = Q + hoff;
  const u16* Kh = K + hoff;
  const u16* Vth = Vt + hoff;
  const int b = pair >> 4, h = pair & 15;
  const float c1 = 0.08838834764831845f * 1.4426950408889634f;
  const float THR = 11.5f;

  int ksr[2], kcc[2], vdr[2], vcc[2];
#pragma unroll
  for (int it = 0; it < 2; ++it) {
    int idx = it * 512 + tid;
    ksr[it] = idx >> 4; kcc[it] = idx & 15;
    vdr[it] = idx >> 3; vcc[it] = idx & 7;
  }

  const int q0 = qb * 128;
  const int nt = 2 * qb + 2;
  const int qw = q0 + w * 16;

  bf16x8 qf[4];
#pragma unroll
  for (int ks = 0; ks < 4; ++ks)
    qf[ks] = *(const bf16x8*)&Qh[(size_t)(qw + fr) * 128 + ks * 32 + fq * 8];

  f32x4 o[8] = {};
  float m2[4], ls[4];
#pragma unroll
  for (int r = 0; r < 4; ++r) { m2[r] = -1e30f; ls[r] = 0.f; }

  u32x4 kst[2], vst[2];
#pragma unroll
  for (int it = 0; it < 2; ++it) {
    kst[it] = *(const u32x4*)&Kh[(size_t)ksr[it] * 128 + kcc[it] * 8];
    vst[it] = *(const u32x4*)&Vth[(size_t)vdr[it] * 2048 + vcc[it] * 8];
  }

  for (int t = 0; t < nt; ++t) {
    const int kv0 = t * 64;
#pragma unroll
    for (int it = 0; it < 2; ++it) {
      *(u32x4*)(lK + ksr[it] * 256 + ((kcc[it] ^ (ksr[it] & 7)) << 4)) = kst[it];
      *(u32x4*)(lV + vdr[it] * 128 + ((vcc[it] ^ (vdr[it] & 7)) << 4)) = vst[it];
    }
    if (t + 1 < nt) {
      const int nk = kv0 + 64;
#pragma unroll
      for (int it = 0; it < 2; ++it) {
        kst[it] = *(const u32x4*)&Kh[(size_t)(nk + ksr[it]) * 128 + kcc[it] * 8];
        vst[it] = *(const u32x4*)&Vth[(size_t)vdr[it] * 2048 + nk + vcc[it] * 8];
      }
    }
    __syncthreads();

    if (kv0 <= qw + 15) {
      f32x4 sc[4] = {};
#pragma unroll
      for (int j = 0; j < 4; ++j) {
        int s = j * 16 + fr;
#pragma unroll
        for (int ks = 0; ks < 4; ++ks) {
          bf16x8 kf = *(const bf16x8*)(lK + s * 256 + (((ks * 32 + fq * 8) * 2) ^ ((s & 7) << 4)));
          sc[j] = MFMA16(qf[ks], kf, sc[j], 0, 0, 0);
        }
      }
      if (kv0 + 64 > qw) {
        int rowb = qw + fq * 4;
#pragma unroll
        for (int j = 0; j < 4; ++j) {
          int col = kv0 + j * 16 + fr;
#pragma unroll
          for (int r = 0; r < 4; ++r)
            if (col > rowb + r) sc[j][r] = -3e38f;
        }
      }
      float lmax[4];
      bool trip = false;
#pragma unroll
      for (int r = 0; r < 4; ++r) {
        lmax[r] = fmaxf(fmaxf(sc[0][r], sc[1][r]), fmaxf(sc[2][r], sc[3][r]));
        trip = trip || (lmax[r] * c1 > m2[r] + THR);
      }
      if (__any(trip)) {
#pragma unroll
        for (int r = 0; r < 4; ++r) {
          float v = lmax[r];
          v = fmaxf(v, __shfl_xor(v, 1));
          v = fmaxf(v, __shfl_xor(v, 2));
          v = fmaxf(v, __shfl_xor(v, 4));
          v = fmaxf(v, __shfl_xor(v, 8));
          v *= c1;
          float mn = fmaxf(m2[r], v);
          float corr = __builtin_amdgcn_exp2f(m2[r] - mn);
          m2[r] = mn;
          ls[r] *= corr;
#pragma unroll
          for (int n = 0; n < 8; ++n) o[n][r] *= corr;
        }
      }
#pragma unroll
      for (int r = 0; r < 4; ++r) {
        int prow = w * 16 + fq * 4 + r;
        float rs = 0.f;
#pragma unroll
        for (int j = 0; j < 4; ++j) {
          float p = __builtin_amdgcn_exp2f(sc[j][r] * c1 - m2[r]);
          rs += p;
          *(u16*)(lP + prow * 128 + (((j * 16 + fr) * 2) ^ ((prow & 7) << 4))) = f2bf(p);
        }
        ls[r] += rs;
      }
      bf16x8 pf[2];
      {
        int prow = w * 16 + fr;
#pragma unroll
        for (int k2 = 0; k2 < 2; ++k2)
          pf[k2] = *(const bf16x8*)(lP + prow * 128 + ((k2 * 64 + fq * 16) ^ ((prow & 7) << 4)));
      }
#pragma unroll
      for (int n = 0; n < 8; ++n) {
        int d = n * 16 + fr;
#pragma unroll
        for (int k2 = 0; k2 < 2; ++k2) {
          bf16x8 vf = *(const bf16x8*)(lV + d * 128 + ((k2 * 64 + fq * 16) ^ ((d & 7) << 4)));
          o[n] = MFMA16(pf[k2], vf, o[n], 0, 0, 0);
        }
      }
    }
    __syncthreads();
  }

  float inv[4];
#pragma unroll
  for (int r = 0; r < 4; ++r) {
    float s = ls[r];
    s += __shfl_xor(s, 1);
    s += __shfl_xor(s, 2);
    s += __shfl_xor(s, 4);
    s += __shfl_xor(s, 8);
    inv[r] = 1.f / s;
  }
#pragma unroll
  for (int n = 0; n < 8; ++n)
#pragma unroll
    for (int r = 0; r < 4; ++r) {
      int tt = qw + fq * 4 + r;
      Y[((size_t)(b * 2048 + tt) * 2048) + h * 128 + n * 16 + fr] = f2bf(o[n][r] * inv[r]);
    }
}

// ---------------------------------------------------------------------------
extern "C" void kernel_launch(void* const* d_in, const int* in_sizes, int n_in,
                              void* d_out, int out_size, void* d_ws, size_t ws_size,
                              hipStream_t stream) {
  const float* x = (const float*)d_in[0];
  const float* Win = (const float*)d_in[1];
  const float* Wout = (const float*)d_in[2];
  float* out = (float*)d_out;
  char* ws = (char*)d_ws;

  u16* x_bf   = (u16*)(ws);                  // 33554432 B
  u16* win_bf = (u16*)(ws + 33554432);       // 25165824 B
  u16* wout_bf= (u16*)(ws + 58720256);       //  8388608 B
  u16* Qb     = (u16*)(ws + 67108864);       // 33554432 B
  u16* Kb     = (u16*)(ws + 100663296);      // 33554432 B
  u16* Vtb    = (u16*)(ws + 134217728);      // 33554432 B (V^T, fused epilogue)
  u16* y_bf   = (u16*)(ws + 167772160);      // 33554432 B  (total 192 MiB)

  convert_all<<<2048, 256, 0, stream>>>(x, Win, Wout, x_bf, win_bf, wout_bf);

  gemm_qkv8<<<768, 512, 0, stream>>>(x_bf, win_bf, Qb, Kb, Vtb);
  attn14<<<dim3(64, 16), 512, 0, stream>>>(Qb, Kb, Vtb, y_bf);
  gemm_out8<<<256, 512, 0, stream>>>(y_bf, wout_bf, out);
}